// Round 1
// baseline (329.127 us; speedup 1.0000x reference)
//
#include <hip/hip_runtime.h>

// MHA: B=2, S=2048, D=1024, H=16, hd=64. All inputs f32; internal bf16 MFMA.
// ws layout (bytes): qb @0 (8MB, B,H,S,hd bf16, pre-scaled by 1/8)
//                    kb @8MB (B,H,S,hd bf16)
//                    vt @16MB (B,H,hd,S bf16 — V transposed for PV B-frags)
//                    ao @24MB (B,S,D bf16 — attention output, input to Wo GEMM)

typedef short bf16x8 __attribute__((ext_vector_type(8)));
typedef short bf16x4 __attribute__((ext_vector_type(4)));
typedef float f32x4 __attribute__((ext_vector_type(4)));

__device__ __forceinline__ short f2bf(float x) {
    unsigned u = __builtin_bit_cast(unsigned, x);
    u += 0x7fffu + ((u >> 16) & 1u);
    return (short)(u >> 16);
}

// ---------------- QKV projection: X(4096x1024) @ W(1024x1024) + b ----------------
// 128x128 tile, BK=32, 4 waves (2x2), each wave 4x4 frags of 16x16x32.
// z=0: queries->qb (scaled 1/8), z=1: keys->kb, z=2: values->vt (transposed store).
__global__ __launch_bounds__(256) void qkv_proj(
    const float* __restrict__ Xq, const float* __restrict__ Xk, const float* __restrict__ Xv,
    const float* __restrict__ Wq, const float* __restrict__ Wk, const float* __restrict__ Wv,
    const float* __restrict__ bq, const float* __restrict__ bk, const float* __restrict__ bv,
    short* __restrict__ qb, short* __restrict__ kb, short* __restrict__ vt)
{
    __shared__ short As[128][40];   // A tile [m][k], pad 40 (80B rows)
    __shared__ short Bs[128][40];   // W tile TRANSPOSED: Bs[n][k]

    const int z = blockIdx.z;
    const float* X; const float* W; const float* bias; float oscale;
    if (z == 0)      { X = Xq; W = Wq; bias = bq; oscale = 0.125f; }
    else if (z == 1) { X = Xk; W = Wk; bias = bk; oscale = 1.0f; }
    else             { X = Xv; W = Wv; bias = bv; oscale = 1.0f; }

    const int tid = threadIdx.x;
    const int m0 = blockIdx.y * 128, n0 = blockIdx.x * 128;
    const int w = tid >> 6, lane = tid & 63, lr = lane & 15, lh = lane >> 4;
    const int wr = (w >> 1) * 64, wc = (w & 1) * 64;

    f32x4 acc[4][4] = {};

    for (int k0 = 0; k0 < 1024; k0 += 32) {
        __syncthreads();
        // stage A: 128x32 f32 -> bf16
        #pragma unroll
        for (int p = 0; p < 4; ++p) {
            int q = tid + p * 256;
            int row = q >> 3, c4 = (q & 7) * 4;
            float4 xv = *(const float4*)(X + (size_t)(m0 + row) * 1024 + k0 + c4);
            bf16x4 sv = { f2bf(xv.x), f2bf(xv.y), f2bf(xv.z), f2bf(xv.w) };
            *(bf16x4*)(&As[row][c4]) = sv;
        }
        // stage B transposed: W[k][n] -> Bs[n][k]
        #pragma unroll
        for (int p = 0; p < 4; ++p) {
            int q = tid + p * 256;
            int k = q >> 5, c4 = (q & 31) * 4;
            float4 wv = *(const float4*)(W + (size_t)(k0 + k) * 1024 + n0 + c4);
            Bs[c4 + 0][k] = f2bf(wv.x);
            Bs[c4 + 1][k] = f2bf(wv.y);
            Bs[c4 + 2][k] = f2bf(wv.z);
            Bs[c4 + 3][k] = f2bf(wv.w);
        }
        __syncthreads();

        bf16x8 af[4], bfr[4];
        #pragma unroll
        for (int mi = 0; mi < 4; ++mi) af[mi] = *(bf16x8*)(&As[wr + mi * 16 + lr][lh * 8]);
        #pragma unroll
        for (int ni = 0; ni < 4; ++ni) bfr[ni] = *(bf16x8*)(&Bs[wc + ni * 16 + lr][lh * 8]);
        #pragma unroll
        for (int mi = 0; mi < 4; ++mi)
            #pragma unroll
            for (int ni = 0; ni < 4; ++ni)
                acc[mi][ni] = __builtin_amdgcn_mfma_f32_16x16x32_bf16(af[mi], bfr[ni], acc[mi][ni], 0, 0, 0);
    }

    // epilogue: bias, scale, head-split store
    #pragma unroll
    for (int ni = 0; ni < 4; ++ni) {
        int c = n0 + wc + ni * 16 + lr;
        float bv_ = bias[c];
        int h = c >> 6, d = c & 63;
        #pragma unroll
        for (int mi = 0; mi < 4; ++mi) {
            #pragma unroll
            for (int j = 0; j < 4; ++j) {
                int r = m0 + wr + mi * 16 + lh * 4 + j;
                int b = r >> 11, s = r & 2047;
                float val = (acc[mi][ni][j] + bv_) * oscale;
                if (z < 2) {
                    short* out = (z == 0) ? qb : kb;
                    out[(((size_t)(b * 16 + h)) * 2048 + s) * 64 + d] = f2bf(val);
                } else {
                    vt[(((size_t)(b * 16 + h)) * 64 + d) * 2048 + s] = f2bf(val);
                }
            }
        }
    }
}

// ---------------- Flash attention (causal), QBLK=128 (4 waves x 32 rows), KBLK=64 ----------------
__global__ __launch_bounds__(256) void attn_fwd(
    const short* __restrict__ qb, const short* __restrict__ kb,
    const short* __restrict__ vt, short* __restrict__ ao)
{
    __shared__ short Ks[64][72];        // K tile [key][hd]
    __shared__ short Vs[64][72];        // V tile [hd][key] (from vt)
    __shared__ short Ps[4][32][72];     // per-wave P relayout buffer

    const int tid = threadIdx.x, w = tid >> 6, lane = tid & 63;
    const int lr = lane & 15, lh = lane >> 4;
    const int bh = blockIdx.y, qblk = blockIdx.x;
    const int q0 = qblk * 128, qw = q0 + w * 32;

    const short* qbase = qb + (size_t)bh * (2048 * 64);
    const short* kbase = kb + (size_t)bh * (2048 * 64);
    const short* vbase = vt + (size_t)bh * (64 * 2048);

    // Q fragments (already scaled by 1/8 at projection)
    bf16x8 aq[2][2];
    #pragma unroll
    for (int mi = 0; mi < 2; ++mi)
        #pragma unroll
        for (int kf = 0; kf < 2; ++kf)
            aq[mi][kf] = *(const bf16x8*)(qbase + (size_t)(qw + mi * 16 + lr) * 64 + kf * 32 + lh * 8);

    float m_i[2][4], l_i[2][4];
    f32x4 o_acc[2][4];
    #pragma unroll
    for (int mi = 0; mi < 2; ++mi)
        #pragma unroll
        for (int j = 0; j < 4; ++j) {
            m_i[mi][j] = -1e30f; l_i[mi][j] = 0.0f;
            o_acc[mi][0][j] = 0.f; o_acc[mi][1][j] = 0.f; o_acc[mi][2][j] = 0.f; o_acc[mi][3][j] = 0.f;
        }

    const int ktiles = 2 * qblk + 2;
    for (int kt = 0; kt < ktiles; ++kt) {
        __syncthreads();
        #pragma unroll
        for (int p = 0; p < 2; ++p) {
            int q = tid + p * 256;
            int row = q >> 3, c8 = (q & 7) * 8;
            *(bf16x8*)(&Ks[row][c8]) = *(const bf16x8*)(kbase + (size_t)(kt * 64 + row) * 64 + c8);
            *(bf16x8*)(&Vs[row][c8]) = *(const bf16x8*)(vbase + (size_t)row * 2048 + kt * 64 + c8);
        }
        __syncthreads();

        const int k0 = kt * 64;
        if (k0 <= qw + 31) {   // not fully masked for this wave (barriers stay uniform)
            // S = Q K^T  (scale pre-folded into Q)
            f32x4 s[2][4] = {};
            #pragma unroll
            for (int kf = 0; kf < 2; ++kf) {
                bf16x8 bk_[4];
                #pragma unroll
                for (int ni = 0; ni < 4; ++ni) bk_[ni] = *(bf16x8*)(&Ks[ni * 16 + lr][kf * 32 + lh * 8]);
                #pragma unroll
                for (int ni = 0; ni < 4; ++ni)
                    #pragma unroll
                    for (int mi = 0; mi < 2; ++mi)
                        s[mi][ni] = __builtin_amdgcn_mfma_f32_16x16x32_bf16(aq[mi][kf], bk_[ni], s[mi][ni], 0, 0, 0);
            }
            // causal mask on diagonal tiles
            if (k0 + 63 > qw) {
                #pragma unroll
                for (int mi = 0; mi < 2; ++mi)
                    #pragma unroll
                    for (int ni = 0; ni < 4; ++ni)
                        #pragma unroll
                        for (int j = 0; j < 4; ++j) {
                            int row = qw + mi * 16 + lh * 4 + j;
                            int col = k0 + ni * 16 + lr;
                            if (col > row) s[mi][ni][j] = -1e30f;
                        }
            }
            // online softmax per row
            #pragma unroll
            for (int mi = 0; mi < 2; ++mi)
                #pragma unroll
                for (int j = 0; j < 4; ++j) {
                    float v = fmaxf(fmaxf(s[mi][0][j], s[mi][1][j]), fmaxf(s[mi][2][j], s[mi][3][j]));
                    v = fmaxf(v, __shfl_xor(v, 1)); v = fmaxf(v, __shfl_xor(v, 2));
                    v = fmaxf(v, __shfl_xor(v, 4)); v = fmaxf(v, __shfl_xor(v, 8));
                    float mold = m_i[mi][j];
                    float mnew = fmaxf(mold, v);
                    float corr = exp2f((mold - mnew) * 1.44269504f);
                    float psum = 0.f;
                    #pragma unroll
                    for (int ni = 0; ni < 4; ++ni) {
                        float p = exp2f((s[mi][ni][j] - mnew) * 1.44269504f);
                        s[mi][ni][j] = p; psum += p;
                    }
                    psum += __shfl_xor(psum, 1); psum += __shfl_xor(psum, 2);
                    psum += __shfl_xor(psum, 4); psum += __shfl_xor(psum, 8);
                    l_i[mi][j] = l_i[mi][j] * corr + psum;
                    m_i[mi][j] = mnew;
                    #pragma unroll
                    for (int ni = 0; ni < 4; ++ni) o_acc[mi][ni][j] *= corr;
                }
            // P (C-layout) -> LDS -> A-layout fragments (wave-local, no block barrier)
            #pragma unroll
            for (int mi = 0; mi < 2; ++mi)
                #pragma unroll
                for (int ni = 0; ni < 4; ++ni)
                    #pragma unroll
                    for (int j = 0; j < 4; ++j)
                        Ps[w][mi * 16 + lh * 4 + j][ni * 16 + lr] = f2bf(s[mi][ni][j]);
            asm volatile("s_waitcnt lgkmcnt(0)" ::: "memory");
            __builtin_amdgcn_sched_barrier(0);
            bf16x8 pa[2][2];
            #pragma unroll
            for (int mi = 0; mi < 2; ++mi)
                #pragma unroll
                for (int kf2 = 0; kf2 < 2; ++kf2)
                    pa[mi][kf2] = *(bf16x8*)(&Ps[w][mi * 16 + lr][kf2 * 32 + lh * 8]);
            // O += P V
            #pragma unroll
            for (int kf2 = 0; kf2 < 2; ++kf2) {
                bf16x8 bv_[4];
                #pragma unroll
                for (int ni = 0; ni < 4; ++ni) bv_[ni] = *(bf16x8*)(&Vs[ni * 16 + lr][kf2 * 32 + lh * 8]);
                #pragma unroll
                for (int ni = 0; ni < 4; ++ni)
                    #pragma unroll
                    for (int mi = 0; mi < 2; ++mi)
                        o_acc[mi][ni] = __builtin_amdgcn_mfma_f32_16x16x32_bf16(pa[mi][kf2], bv_[ni], o_acc[mi][ni], 0, 0, 0);
            }
        }
    }

    // epilogue: normalize, store to ao (B,S,D) bf16
    const int b = bh >> 4, h = bh & 15;
    #pragma unroll
    for (int mi = 0; mi < 2; ++mi)
        #pragma unroll
        for (int j = 0; j < 4; ++j) {
            float rl = 1.0f / l_i[mi][j];
            int row = qw + mi * 16 + lh * 4 + j;
            #pragma unroll
            for (int ni = 0; ni < 4; ++ni) {
                int d = h * 64 + ni * 16 + lr;
                ao[((size_t)(b * 2048 + row)) * 1024 + d] = f2bf(o_acc[mi][ni][j] * rl);
            }
        }
}

// ---------------- Output projection: ao(4096x1024 bf16) @ Wo + bo -> f32 out ----------------
__global__ __launch_bounds__(256) void out_proj(
    const short* __restrict__ ao, const float* __restrict__ Wo,
    const float* __restrict__ bo, float* __restrict__ out)
{
    __shared__ short As[128][40];
    __shared__ short Bs[128][40];   // Wo transposed: Bs[n][k]

    const int tid = threadIdx.x;
    const int m0 = blockIdx.y * 128, n0 = blockIdx.x * 128;
    const int w = tid >> 6, lane = tid & 63, lr = lane & 15, lh = lane >> 4;
    const int wr = (w >> 1) * 64, wc = (w & 1) * 64;

    f32x4 acc[4][4] = {};

    for (int k0 = 0; k0 < 1024; k0 += 32) {
        __syncthreads();
        #pragma unroll
        for (int p = 0; p < 2; ++p) {
            int q = tid + p * 256;
            int row = q >> 2, c8 = (q & 3) * 8;
            *(bf16x8*)(&As[row][c8]) = *(const bf16x8*)(ao + (size_t)(m0 + row) * 1024 + k0 + c8);
        }
        #pragma unroll
        for (int p = 0; p < 4; ++p) {
            int q = tid + p * 256;
            int k = q >> 5, c4 = (q & 31) * 4;
            float4 wv = *(const float4*)(Wo + (size_t)(k0 + k) * 1024 + n0 + c4);
            Bs[c4 + 0][k] = f2bf(wv.x);
            Bs[c4 + 1][k] = f2bf(wv.y);
            Bs[c4 + 2][k] = f2bf(wv.z);
            Bs[c4 + 3][k] = f2bf(wv.w);
        }
        __syncthreads();

        bf16x8 af[4], bfr[4];
        #pragma unroll
        for (int mi = 0; mi < 4; ++mi) af[mi] = *(bf16x8*)(&As[wr + mi * 16 + lr][lh * 8]);
        #pragma unroll
        for (int ni = 0; ni < 4; ++ni) bfr[ni] = *(bf16x8*)(&Bs[wc + ni * 16 + lr][lh * 8]);
        #pragma unroll
        for (int mi = 0; mi < 4; ++mi)
            #pragma unroll
            for (int ni = 0; ni < 4; ++ni)
                acc[mi][ni] = __builtin_amdgcn_mfma_f32_16x16x32_bf16(af[mi], bfr[ni], acc[mi][ni], 0, 0, 0);
    }

    #pragma unroll
    for (int ni = 0; ni < 4; ++ni) {
        int c = n0 + wc + ni * 16 + lr;
        float bv_ = bo[c];
        #pragma unroll
        for (int mi = 0; mi < 4; ++mi) {
            #pragma unroll
            for (int j = 0; j < 4; ++j) {
                int r = m0 + wr + mi * 16 + lh * 4 + j;
                out[(size_t)r * 1024 + c] = acc[mi][ni][j] + bv_;
            }
        }
    }
}

extern "C" void kernel_launch(void* const* d_in, const int* in_sizes, int n_in,
                              void* d_out, int out_size, void* d_ws, size_t ws_size,
                              hipStream_t stream) {
    const float* queries = (const float*)d_in[0];
    const float* keys    = (const float*)d_in[1];
    const float* values  = (const float*)d_in[2];
    const float* Wq = (const float*)d_in[3];  const float* bq = (const float*)d_in[4];
    const float* Wk = (const float*)d_in[5];  const float* bk = (const float*)d_in[6];
    const float* Wv = (const float*)d_in[7];  const float* bv = (const float*)d_in[8];
    const float* Wo = (const float*)d_in[9];  const float* bo = (const float*)d_in[10];
    float* out = (float*)d_out;

    char* ws = (char*)d_ws;
    short* qb = (short*)(ws);
    short* kb = (short*)(ws + (8u  << 20));
    short* vt = (short*)(ws + (16u << 20));
    short* ao = (short*)(ws + (24u << 20));

    qkv_proj<<<dim3(8, 32, 3), 256, 0, stream>>>(queries, keys, values,
                                                 Wq, Wk, Wv, bq, bk, bv, qb, kb, vt);
    attn_fwd<<<dim3(16, 32), 256, 0, stream>>>(qb, kb, vt, ao);
    out_proj<<<dim3(8, 32), 256, 0, stream>>>(ao, Wo, bo, out);
}

// Round 2
// 202.030 us; speedup vs baseline: 1.6291x; 1.6291x over previous
//
#include <hip/hip_runtime.h>

// MHA: B=2, S=2048, D=1024, H=16, hd=64. f32 I/O, bf16 MFMA internally.
// ws layout (bytes):
//   xb @0     : 24MB  bf16 [3][4096][1024]  (converted queries/keys/values)
//   qb @24MB  : 8MB   bf16 [B*H][2048][64]  (pre-scaled 1/8)
//   kb @32MB  : 8MB   bf16 [B*H][2048][64]
//   vt @40MB  : 8MB   bf16 [B*H][64][2048]  (V transposed)
//   wb @48MB  : 8MB   bf16 [4][1024][1024]  W^T (n-major) for Wq,Wk,Wv,Wo
//   ao @0     : 8MB   bf16 [4096][1024]     (reuses dead xb region)
// total 56MB.

typedef short bf16x8 __attribute__((ext_vector_type(8)));
typedef short bf16x4 __attribute__((ext_vector_type(4)));
typedef short bf16x2 __attribute__((ext_vector_type(2)));
typedef float f32x4 __attribute__((ext_vector_type(4)));

#define LOG2E 1.44269504f

__device__ __forceinline__ short f2bf(float x) {
    unsigned u = __builtin_bit_cast(unsigned, x);
    u += 0x7fffu + ((u >> 16) & 1u);
    return (short)(u >> 16);
}

__device__ __forceinline__ void gload16(const short* g, short* l) {
    __builtin_amdgcn_global_load_lds((const __attribute__((address_space(1))) void*)g,
                                     (__attribute__((address_space(3))) void*)l, 16, 0, 0);
}

// ---------------- convert X (3 tensors) f32 -> bf16 ----------------
__global__ __launch_bounds__(256) void cvt_x(
    const float* __restrict__ xq, const float* __restrict__ xk,
    const float* __restrict__ xv, short* __restrict__ xb)
{
    size_t g = (size_t)blockIdx.x * 256 + threadIdx.x;   // 1,572,864 total
    int z = (int)(g >> 19);                              // 524288 groups of 8 per tensor
    size_t off = (g & 524287) * 8;
    const float* src = (z == 0) ? xq : (z == 1) ? xk : xv;
    float4 a = *(const float4*)(src + off);
    float4 b = *(const float4*)(src + off + 4);
    bf16x8 o = { f2bf(a.x), f2bf(a.y), f2bf(a.z), f2bf(a.w),
                 f2bf(b.x), f2bf(b.y), f2bf(b.z), f2bf(b.w) };
    *(bf16x8*)(xb + (size_t)z * 4194304 + off) = o;
}

// ---------------- convert + transpose W: [k][n] f32 -> wb[z][n][k] bf16 ----------------
__global__ __launch_bounds__(256) void cvt_w(
    const float* __restrict__ Wq, const float* __restrict__ Wk,
    const float* __restrict__ Wv, const float* __restrict__ Wo,
    short* __restrict__ wb)
{
    __shared__ short T[64][72];   // [n][k], rows 144B (16B-aligned for b128 reads)
    const int z = blockIdx.z;
    const float* W = (z == 0) ? Wq : (z == 1) ? Wk : (z == 2) ? Wv : Wo;
    const int k0 = blockIdx.y * 64, n0 = blockIdx.x * 64;
    const int tid = threadIdx.x;

    #pragma unroll
    for (int p = 0; p < 4; ++p) {
        int idx = p * 256 + tid;
        int r = idx >> 4, c4 = (idx & 15) * 4;
        float4 wv = *(const float4*)(W + (size_t)(k0 + r) * 1024 + n0 + c4);
        T[c4 + 0][r] = f2bf(wv.x);
        T[c4 + 1][r] = f2bf(wv.y);
        T[c4 + 2][r] = f2bf(wv.z);
        T[c4 + 3][r] = f2bf(wv.w);
    }
    __syncthreads();
    #pragma unroll
    for (int p = 0; p < 2; ++p) {
        int idx = p * 256 + tid;
        int n = idx >> 3, c8 = (idx & 7) * 8;
        *(bf16x8*)(wb + (size_t)z * 1048576 + (size_t)(n0 + n) * 1024 + k0 + c8) =
            *(const bf16x8*)(&T[n][c8]);
    }
}

// ---------------- m97-style GEMM core: 128x128 tile, BK=64, gload_lds + XOR swizzle ----------------
// A bf16 [M][1024], Bt bf16 [n][k]. 4 waves (2x2), 4x4 frags/wave, 2 kf per K-step.
#define GEMM_CORE(A_, Bt_, ACC_)                                                         \
    const short* srcA[4]; const short* srcB[4]; short* dstA[4]; short* dstB[4];          \
    _Pragma("unroll")                                                                    \
    for (int p = 0; p < 4; ++p) {                                                        \
        int idx = p * 256 + tid;                                                         \
        int row = idx >> 3;                                                              \
        int c8 = (idx & 7) ^ (row & 7);                                                  \
        srcA[p] = (A_)  + (size_t)(m0 + row) * 1024 + c8 * 8;                            \
        srcB[p] = (Bt_) + (size_t)(n0 + row) * 1024 + c8 * 8;                            \
        dstA[p] = As + idx * 8;                                                          \
        dstB[p] = Bs + idx * 8;                                                          \
    }                                                                                    \
    for (int k0 = 0; k0 < 1024; k0 += 64) {                                              \
        __syncthreads();                                                                 \
        _Pragma("unroll")                                                                \
        for (int p = 0; p < 4; ++p) {                                                    \
            gload16(srcA[p] + k0, dstA[p]);                                              \
            gload16(srcB[p] + k0, dstB[p]);                                              \
        }                                                                                \
        __syncthreads();                                                                 \
        _Pragma("unroll")                                                                \
        for (int kf = 0; kf < 2; ++kf) {                                                 \
            bf16x8 af[4], bfr[4];                                                        \
            _Pragma("unroll")                                                            \
            for (int mi = 0; mi < 4; ++mi) {                                             \
                int row = wr + mi * 16 + lr;                                             \
                af[mi] = *(const bf16x8*)(As + row * 64 + (((kf << 2) | lh) ^ (row & 7)) * 8); \
            }                                                                            \
            _Pragma("unroll")                                                            \
            for (int ni = 0; ni < 4; ++ni) {                                             \
                int row = wc + ni * 16 + lr;                                             \
                bfr[ni] = *(const bf16x8*)(Bs + row * 64 + (((kf << 2) | lh) ^ (row & 7)) * 8); \
            }                                                                            \
            _Pragma("unroll")                                                            \
            for (int mi = 0; mi < 4; ++mi)                                               \
                _Pragma("unroll")                                                        \
                for (int ni = 0; ni < 4; ++ni)                                           \
                    ACC_[mi][ni] = __builtin_amdgcn_mfma_f32_16x16x32_bf16(af[mi], bfr[ni], ACC_[mi][ni], 0, 0, 0); \
        }                                                                                \
    }

__global__ __launch_bounds__(256, 3) void qkv_gemm(
    const short* __restrict__ xb, const short* __restrict__ wb,
    const float* __restrict__ bq, const float* __restrict__ bk, const float* __restrict__ bv,
    short* __restrict__ qb, short* __restrict__ kb, short* __restrict__ vt)
{
    __shared__ short As[128 * 64];
    __shared__ short Bs[128 * 64];
    const int z = blockIdx.z;
    const short* A  = xb + (size_t)z * 4194304;
    const short* Bt = wb + (size_t)z * 1048576;
    const float* bias = (z == 0) ? bq : (z == 1) ? bk : bv;
    const float oscale = (z == 0) ? 0.125f : 1.0f;

    const int tid = threadIdx.x;
    const int m0 = blockIdx.y * 128, n0 = blockIdx.x * 128;
    const int w = tid >> 6, lane = tid & 63, lr = lane & 15, lh = lane >> 4;
    const int wr = (w >> 1) * 64, wc = (w & 1) * 64;

    f32x4 acc[4][4] = {};
    GEMM_CORE(A, Bt, acc)

    #pragma unroll
    for (int ni = 0; ni < 4; ++ni) {
        int c = n0 + wc + ni * 16 + lr;
        float bv_ = bias[c];
        int h = c >> 6, d = c & 63;
        #pragma unroll
        for (int mi = 0; mi < 4; ++mi) {
            #pragma unroll
            for (int j = 0; j < 4; ++j) {
                int r = m0 + wr + mi * 16 + lh * 4 + j;
                int b = r >> 11, s = r & 2047;
                float val = (acc[mi][ni][j] + bv_) * oscale;
                if (z < 2) {
                    short* o = (z == 0) ? qb : kb;
                    o[(((size_t)(b * 16 + h)) * 2048 + s) * 64 + d] = f2bf(val);
                } else {
                    vt[(((size_t)(b * 16 + h)) * 64 + d) * 2048 + s] = f2bf(val);
                }
            }
        }
    }
}

__global__ __launch_bounds__(256, 3) void out_gemm(
    const short* __restrict__ ao, const short* __restrict__ wbo,
    const float* __restrict__ bo, float* __restrict__ out)
{
    __shared__ short As[128 * 64];
    __shared__ short Bs[128 * 64];
    const int tid = threadIdx.x;
    const int m0 = blockIdx.y * 128, n0 = blockIdx.x * 128;
    const int w = tid >> 6, lane = tid & 63, lr = lane & 15, lh = lane >> 4;
    const int wr = (w >> 1) * 64, wc = (w & 1) * 64;

    f32x4 acc[4][4] = {};
    GEMM_CORE(ao, wbo, acc)

    #pragma unroll
    for (int ni = 0; ni < 4; ++ni) {
        int c = n0 + wc + ni * 16 + lr;
        float bv_ = bo[c];
        #pragma unroll
        for (int mi = 0; mi < 4; ++mi) {
            #pragma unroll
            for (int j = 0; j < 4; ++j) {
                int r = m0 + wr + mi * 16 + lh * 4 + j;
                out[(size_t)r * 1024 + c] = acc[mi][ni][j] + bv_;
            }
        }
    }
}

// ---------------- attention: swapped-operand flash, no block barriers ----------------
// Per wave: 32 q-rows. S^T = mfma(K, Q) so each lane owns 2 q-rows (16 keys in-reg each).
// K/V read directly from L2 (no LDS staging). P^T relayout via per-wave LDS.
__global__ __launch_bounds__(256) void attn_fwd2(
    const short* __restrict__ qb, const short* __restrict__ kb,
    const short* __restrict__ vt, short* __restrict__ ao)
{
    __shared__ short Ps[4][32][76];   // per-wave P^T buffer [q][key], rows 152B
    const int tid = threadIdx.x, w = tid >> 6, lane = tid & 63;
    const int lr = lane & 15, lh = lane >> 4;

    // XCD-clustered decode: xcd gets bh in [4*xcd, 4*xcd+4); big q-blocks first.
    const int bid = blockIdx.x;
    const int xcd = bid & 7, jj = bid >> 3;
    const int bh = xcd * 4 + (jj >> 4);
    const int qblk = 15 - (jj & 15);
    const int qw = qblk * 128 + w * 32;

    const short* qbase = qb + (size_t)bh * (2048 * 64);
    const short* kbase = kb + (size_t)bh * (2048 * 64);
    const short* vbase = vt + (size_t)bh * (64 * 2048);

    bf16x8 aq[2][2];
    #pragma unroll
    for (int ni = 0; ni < 2; ++ni)
        #pragma unroll
        for (int kf = 0; kf < 2; ++kf)
            aq[ni][kf] = *(const bf16x8*)(qbase + (size_t)(qw + ni * 16 + lr) * 64 + kf * 32 + lh * 8);

    float m_i[2] = { -1e30f, -1e30f }, l_i[2] = { 0.f, 0.f };
    f32x4 o_acc[4][2] = {};

    const int ktiles = qw / 64 + 1;
    for (int kt = 0; kt < ktiles; ++kt) {
        const int k0 = kt * 64;
        // S^T[key][q]
        f32x4 s[4][2] = {};
        #pragma unroll
        for (int kf = 0; kf < 2; ++kf) {
            bf16x8 ak[4];
            #pragma unroll
            for (int mi = 0; mi < 4; ++mi)
                ak[mi] = *(const bf16x8*)(kbase + (size_t)(k0 + mi * 16 + lr) * 64 + kf * 32 + lh * 8);
            #pragma unroll
            for (int mi = 0; mi < 4; ++mi)
                #pragma unroll
                for (int ni = 0; ni < 2; ++ni)
                    s[mi][ni] = __builtin_amdgcn_mfma_f32_16x16x32_bf16(ak[mi], aq[ni][kf], s[mi][ni], 0, 0, 0);
        }
        // causal mask (diagonal tiles only)
        if (k0 + 63 > qw) {
            #pragma unroll
            for (int mi = 0; mi < 4; ++mi)
                #pragma unroll
                for (int ni = 0; ni < 2; ++ni)
                    #pragma unroll
                    for (int j = 0; j < 4; ++j) {
                        int key = k0 + mi * 16 + lh * 4 + j;
                        int q   = qw + ni * 16 + lr;
                        if (key > q) s[mi][ni][j] = -1e30f;
                    }
        }
        // online softmax: per lane only 2 q-rows; 16 in-lane values + 2 shfl
        #pragma unroll
        for (int ni = 0; ni < 2; ++ni) {
            float v = s[0][ni][0];
            #pragma unroll
            for (int mi = 0; mi < 4; ++mi)
                #pragma unroll
                for (int j = 0; j < 4; ++j)
                    v = fmaxf(v, s[mi][ni][j]);
            v = fmaxf(v, __shfl_xor(v, 16));
            v = fmaxf(v, __shfl_xor(v, 32));
            float mnew = fmaxf(m_i[ni], v);
            float corr = exp2f((m_i[ni] - mnew) * LOG2E);
            m_i[ni] = mnew;
            float psum = 0.f;
            #pragma unroll
            for (int mi = 0; mi < 4; ++mi)
                #pragma unroll
                for (int j = 0; j < 4; ++j) {
                    float p = exp2f((s[mi][ni][j] - mnew) * LOG2E);
                    s[mi][ni][j] = p;
                    psum += p;
                }
            psum += __shfl_xor(psum, 16);
            psum += __shfl_xor(psum, 32);
            l_i[ni] = l_i[ni] * corr + psum;
            #pragma unroll
            for (int mi = 0; mi < 4; ++mi)
                o_acc[mi][ni] *= corr;
        }
        // P^T -> per-wave LDS [q][key]
        #pragma unroll
        for (int ni = 0; ni < 2; ++ni)
            #pragma unroll
            for (int mi = 0; mi < 4; ++mi) {
                bf16x2 p01 = { f2bf(s[mi][ni][0]), f2bf(s[mi][ni][1]) };
                bf16x2 p23 = { f2bf(s[mi][ni][2]), f2bf(s[mi][ni][3]) };
                *(bf16x2*)(&Ps[w][ni * 16 + lr][mi * 16 + lh * 4])     = p01;
                *(bf16x2*)(&Ps[w][ni * 16 + lr][mi * 16 + lh * 4 + 2]) = p23;
            }
        asm volatile("s_waitcnt lgkmcnt(0)" ::: "memory");
        __builtin_amdgcn_sched_barrier(0);
        // O^T += V^T P^T
        #pragma unroll
        for (int kf = 0; kf < 2; ++kf) {
            bf16x8 av[4], pb[2];
            #pragma unroll
            for (int mi = 0; mi < 4; ++mi)
                av[mi] = *(const bf16x8*)(vbase + (size_t)(mi * 16 + lr) * 2048 + k0 + kf * 32 + lh * 8);
            #pragma unroll
            for (int ni = 0; ni < 2; ++ni)
                pb[ni] = *(const bf16x8*)(&Ps[w][ni * 16 + lr][kf * 32 + lh * 8]);
            #pragma unroll
            for (int mi = 0; mi < 4; ++mi)
                #pragma unroll
                for (int ni = 0; ni < 2; ++ni)
                    o_acc[mi][ni] = __builtin_amdgcn_mfma_f32_16x16x32_bf16(av[mi], pb[ni], o_acc[mi][ni], 0, 0, 0);
        }
    }

    // epilogue: normalize, store O (q rows, d cols) to ao (B,S,D)
    const int b = bh >> 4, h = bh & 15;
    #pragma unroll
    for (int ni = 0; ni < 2; ++ni) {
        float rl = 1.0f / l_i[ni];
        int q = qw + ni * 16 + lr;
        #pragma unroll
        for (int mi = 0; mi < 4; ++mi) {
            bf16x4 o4 = { f2bf(o_acc[mi][ni][0] * rl), f2bf(o_acc[mi][ni][1] * rl),
                          f2bf(o_acc[mi][ni][2] * rl), f2bf(o_acc[mi][ni][3] * rl) };
            *(bf16x4*)(ao + ((size_t)(b * 2048 + q)) * 1024 + h * 64 + mi * 16 + lh * 4) = o4;
        }
    }
}

extern "C" void kernel_launch(void* const* d_in, const int* in_sizes, int n_in,
                              void* d_out, int out_size, void* d_ws, size_t ws_size,
                              hipStream_t stream) {
    const float* queries = (const float*)d_in[0];
    const float* keys    = (const float*)d_in[1];
    const float* values  = (const float*)d_in[2];
    const float* Wq = (const float*)d_in[3];  const float* bq = (const float*)d_in[4];
    const float* Wk = (const float*)d_in[5];  const float* bk = (const float*)d_in[6];
    const float* Wv = (const float*)d_in[7];  const float* bv = (const float*)d_in[8];
    const float* Wo = (const float*)d_in[9];  const float* bo = (const float*)d_in[10];
    float* out = (float*)d_out;

    char* ws = (char*)d_ws;
    short* xb = (short*)(ws);                   // 24MB
    short* qb = (short*)(ws + (24u << 20));     // 8MB
    short* kb = (short*)(ws + (32u << 20));     // 8MB
    short* vt = (short*)(ws + (40u << 20));     // 8MB
    short* wb = (short*)(ws + (48u << 20));     // 8MB
    short* ao = (short*)(ws);                   // 8MB, reuses xb after qkv_gemm

    cvt_x<<<6144, 256, 0, stream>>>(queries, keys, values, xb);
    cvt_w<<<dim3(16, 16, 4), 256, 0, stream>>>(Wq, Wk, Wv, Wo, wb);
    qkv_gemm<<<dim3(8, 32, 3), 256, 0, stream>>>(xb, wb, bq, bk, bv, qb, kb, vt);
    attn_fwd2<<<512, 256, 0, stream>>>(qb, kb, vt, ao);
    out_gemm<<<dim3(8, 32), 256, 0, stream>>>(ao, wb + (size_t)3 * 1048576, bo, out);
}

// Round 3
// 160.377 us; speedup vs baseline: 2.0522x; 1.2597x over previous
//
#include <hip/hip_runtime.h>

// MHA: B=2, S=2048, D=1024, H=16, hd=64. f32 I/O, bf16 MFMA internally.
// ws layout (bytes):
//   xb @0     : 24MB  bf16 [3][4096][1024]  (converted queries/keys/values)
//   qb @24MB  : 8MB   bf16 [B*H][2048][64]  (pre-scaled by 0.125*log2e)
//   kb @32MB  : 8MB   bf16 [B*H][2048][64]
//   vt @40MB  : 8MB   bf16 [B*H][64][2048]  (V transposed)
//   wb @48MB  : 8MB   bf16 [4][1024][1024]  W^T (n-major) for Wq,Wk,Wv,Wo
//   ao @0     : 8MB   bf16 [4096][1024]     (reuses dead xb region)

typedef short bf16x8 __attribute__((ext_vector_type(8)));
typedef short bf16x4 __attribute__((ext_vector_type(4)));
typedef float f32x4 __attribute__((ext_vector_type(4)));
typedef float f32x16 __attribute__((ext_vector_type(16)));
typedef unsigned u32x4 __attribute__((ext_vector_type(4)));

#define LOG2E 1.44269504f

__device__ __forceinline__ short f2bf(float x) {
    unsigned u = __builtin_bit_cast(unsigned, x);
    u += 0x7fffu + ((u >> 16) & 1u);
    return (short)(u >> 16);
}

__device__ __forceinline__ unsigned cvtpk(float lo, float hi) {
    unsigned r;
    asm("v_cvt_pk_bf16_f32 %0, %1, %2" : "=v"(r) : "v"(lo), "v"(hi));
    return r;
}

__device__ __forceinline__ void gload16(const short* g, short* l) {
    __builtin_amdgcn_global_load_lds((const __attribute__((address_space(1))) void*)g,
                                     (__attribute__((address_space(3))) void*)l, 16, 0, 0);
}

// ---------------- convert X (3 tensors) f32 -> bf16 ----------------
__global__ __launch_bounds__(256) void cvt_x(
    const float* __restrict__ xq, const float* __restrict__ xk,
    const float* __restrict__ xv, short* __restrict__ xb)
{
    size_t g = (size_t)blockIdx.x * 256 + threadIdx.x;
    int z = (int)(g >> 19);
    size_t off = (g & 524287) * 8;
    const float* src = (z == 0) ? xq : (z == 1) ? xk : xv;
    float4 a = *(const float4*)(src + off);
    float4 b = *(const float4*)(src + off + 4);
    bf16x8 o = { f2bf(a.x), f2bf(a.y), f2bf(a.z), f2bf(a.w),
                 f2bf(b.x), f2bf(b.y), f2bf(b.z), f2bf(b.w) };
    *(bf16x8*)(xb + (size_t)z * 4194304 + off) = o;
}

// ---------------- convert + transpose W: [k][n] f32 -> wb[z][n][k] bf16 ----------------
__global__ __launch_bounds__(256) void cvt_w(
    const float* __restrict__ Wq, const float* __restrict__ Wk,
    const float* __restrict__ Wv, const float* __restrict__ Wo,
    short* __restrict__ wb)
{
    __shared__ short T[64][72];
    const int z = blockIdx.z;
    const float* W = (z == 0) ? Wq : (z == 1) ? Wk : (z == 2) ? Wv : Wo;
    const int k0 = blockIdx.y * 64, n0 = blockIdx.x * 64;
    const int tid = threadIdx.x;

    #pragma unroll
    for (int p = 0; p < 4; ++p) {
        int idx = p * 256 + tid;
        int r = idx >> 4, c4 = (idx & 15) * 4;
        float4 wv = *(const float4*)(W + (size_t)(k0 + r) * 1024 + n0 + c4);
        T[c4 + 0][r] = f2bf(wv.x);
        T[c4 + 1][r] = f2bf(wv.y);
        T[c4 + 2][r] = f2bf(wv.z);
        T[c4 + 3][r] = f2bf(wv.w);
    }
    __syncthreads();
    #pragma unroll
    for (int p = 0; p < 2; ++p) {
        int idx = p * 256 + tid;
        int n = idx >> 3, c8 = (idx & 7) * 8;
        *(bf16x8*)(wb + (size_t)z * 1048576 + (size_t)(n0 + n) * 1024 + k0 + c8) =
            *(const bf16x8*)(&T[n][c8]);
    }
}

// ---------------- m97-style GEMM core: 128x128 tile, BK=64, gload_lds + XOR swizzle ----------------
#define GEMM_CORE(A_, Bt_, ACC_)                                                         \
    const short* srcA[4]; const short* srcB[4]; short* dstA[4]; short* dstB[4];          \
    _Pragma("unroll")                                                                    \
    for (int p = 0; p < 4; ++p) {                                                        \
        int idx = p * 256 + tid;                                                         \
        int row = idx >> 3;                                                              \
        int c8 = (idx & 7) ^ (row & 7);                                                  \
        srcA[p] = (A_)  + (size_t)(m0 + row) * 1024 + c8 * 8;                            \
        srcB[p] = (Bt_) + (size_t)(n0 + row) * 1024 + c8 * 8;                            \
        dstA[p] = As + idx * 8;                                                          \
        dstB[p] = Bs + idx * 8;                                                          \
    }                                                                                    \
    for (int k0 = 0; k0 < 1024; k0 += 64) {                                              \
        __syncthreads();                                                                 \
        _Pragma("unroll")                                                                \
        for (int p = 0; p < 4; ++p) {                                                    \
            gload16(srcA[p] + k0, dstA[p]);                                              \
            gload16(srcB[p] + k0, dstB[p]);                                              \
        }                                                                                \
        __syncthreads();                                                                 \
        _Pragma("unroll")                                                                \
        for (int kf = 0; kf < 2; ++kf) {                                                 \
            bf16x8 af[4], bfr[4];                                                        \
            _Pragma("unroll")                                                            \
            for (int mi = 0; mi < 4; ++mi) {                                             \
                int row = wr + mi * 16 + lr;                                             \
                af[mi] = *(const bf16x8*)(As + row * 64 + (((kf << 2) | lh) ^ (row & 7)) * 8); \
            }                                                                            \
            _Pragma("unroll")                                                            \
            for (int ni = 0; ni < 4; ++ni) {                                             \
                int row = wc + ni * 16 + lr;                                             \
                bfr[ni] = *(const bf16x8*)(Bs + row * 64 + (((kf << 2) | lh) ^ (row & 7)) * 8); \
            }                                                                            \
            _Pragma("unroll")                                                            \
            for (int mi = 0; mi < 4; ++mi)                                               \
                _Pragma("unroll")                                                        \
                for (int ni = 0; ni < 4; ++ni)                                           \
                    ACC_[mi][ni] = __builtin_amdgcn_mfma_f32_16x16x32_bf16(af[mi], bfr[ni], ACC_[mi][ni], 0, 0, 0); \
        }                                                                                \
    }

__global__ __launch_bounds__(256, 3) void qkv_gemm(
    const short* __restrict__ xb, const short* __restrict__ wb,
    const float* __restrict__ bq, const float* __restrict__ bk, const float* __restrict__ bv,
    short* __restrict__ qb, short* __restrict__ kb, short* __restrict__ vt)
{
    __shared__ short As[128 * 64];
    __shared__ short Bs[128 * 64];
    const int z = blockIdx.z;
    const short* A  = xb + (size_t)z * 4194304;
    const short* Bt = wb + (size_t)z * 1048576;
    const float* bias = (z == 0) ? bq : (z == 1) ? bk : bv;
    // q pre-scaled by 1/sqrt(hd) * log2(e) so attention softmax uses exp2 directly
    const float oscale = (z == 0) ? (0.125f * LOG2E) : 1.0f;

    const int tid = threadIdx.x;
    const int m0 = blockIdx.y * 128, n0 = blockIdx.x * 128;
    const int w = tid >> 6, lane = tid & 63, lr = lane & 15, lh = lane >> 4;
    const int wr = (w >> 1) * 64, wc = (w & 1) * 64;

    f32x4 acc[4][4] = {};
    GEMM_CORE(A, Bt, acc)

    #pragma unroll
    for (int ni = 0; ni < 4; ++ni) {
        int c = n0 + wc + ni * 16 + lr;
        float bv_ = bias[c];
        int h = c >> 6, d = c & 63;
        #pragma unroll
        for (int mi = 0; mi < 4; ++mi) {
            #pragma unroll
            for (int j = 0; j < 4; ++j) {
                int r = m0 + wr + mi * 16 + lh * 4 + j;
                int b = r >> 11, s = r & 2047;
                float val = (acc[mi][ni][j] + bv_) * oscale;
                if (z < 2) {
                    short* o = (z == 0) ? qb : kb;
                    o[(((size_t)(b * 16 + h)) * 2048 + s) * 64 + d] = f2bf(val);
                } else {
                    vt[(((size_t)(b * 16 + h)) * 64 + d) * 2048 + s] = f2bf(val);
                }
            }
        }
    }
}

__global__ __launch_bounds__(256, 3) void out_gemm(
    const short* __restrict__ ao, const short* __restrict__ wbo,
    const float* __restrict__ bo, float* __restrict__ out)
{
    __shared__ short As[128 * 64];
    __shared__ short Bs[128 * 64];
    const int tid = threadIdx.x;
    const int m0 = blockIdx.y * 128, n0 = blockIdx.x * 128;
    const int w = tid >> 6, lane = tid & 63, lr = lane & 15, lh = lane >> 4;
    const int wr = (w >> 1) * 64, wc = (w & 1) * 64;

    f32x4 acc[4][4] = {};
    GEMM_CORE(ao, wbo, acc)

    #pragma unroll
    for (int ni = 0; ni < 4; ++ni) {
        int c = n0 + wc + ni * 16 + lr;
        float bv_ = bo[c];
        #pragma unroll
        for (int mi = 0; mi < 4; ++mi) {
            #pragma unroll
            for (int j = 0; j < 4; ++j) {
                int r = m0 + wr + mi * 16 + lh * 4 + j;
                out[(size_t)r * 1024 + c] = acc[mi][ni][j] + bv_;
            }
        }
    }
}

// ---------------- attention: 1-wave blocks, 32x32 MFMA, in-register softmax ----------------
// Per wave: 32 q-rows (strip), KBLK=64. S^T = mfma(K,Q): each lane owns ONE q-row
// (col=lane&31), 32 P-values in-lane. Row reduce: 31 in-lane + 1 shfl_xor(32).
// P->B-frag: 16 cvt_pk + 8 permlane32_swap (m214-v22 recipe). No LDS at all.

__device__ __forceinline__ void load_kf(bf16x8 (&kf)[2][4], const short* kbase, int k0, int r, int h) {
    #pragma unroll
    for (int m = 0; m < 2; ++m)
        #pragma unroll
        for (int kk = 0; kk < 4; ++kk)
            kf[m][kk] = *(const bf16x8*)(kbase + (size_t)(k0 + m * 32 + r) * 64 + kk * 16 + h * 8);
}

__device__ __forceinline__ void load_vf(bf16x8 (&vf)[2][4], const short* vbase, int k0, int r, int h) {
    #pragma unroll
    for (int dm = 0; dm < 2; ++dm)
        #pragma unroll
        for (int ks = 0; ks < 4; ++ks)
            vf[dm][ks] = *(const bf16x8*)(vbase + (size_t)(dm * 32 + r) * 2048 + k0 + ks * 16 + h * 8);
}

__device__ __forceinline__ void qk_mfma(f32x16& s0, f32x16& s1,
                                        const bf16x8 (&kf)[2][4], const bf16x8 (&aq)[4]) {
    #pragma unroll
    for (int kk = 0; kk < 4; ++kk) {
        s0 = __builtin_amdgcn_mfma_f32_32x32x16_bf16(kf[0][kk], aq[kk], s0, 0, 0, 0);
        s1 = __builtin_amdgcn_mfma_f32_32x32x16_bf16(kf[1][kk], aq[kk], s1, 0, 0, 0);
    }
}

template<bool MASK>
__device__ __forceinline__ void sm_pv(f32x16& s0, f32x16& s1, const bf16x8 (&av)[2][4],
                                      int k0, int q, int h,
                                      float& m_i, float& l_i, f32x16& o0, f32x16& o1)
{
    if (MASK) {
        #pragma unroll
        for (int m = 0; m < 2; ++m) {
            f32x16& sv = m ? s1 : s0;
            #pragma unroll
            for (int p = 0; p < 16; ++p) {
                int key = k0 + m * 32 + (p & 3) + 8 * (p >> 2) + 4 * h;
                if (key > q) sv[p] = -1e30f;
            }
        }
    }
    // in-lane max (tree)
    float mx[16];
    #pragma unroll
    for (int p = 0; p < 16; ++p) mx[p] = fmaxf(s0[p], s1[p]);
    #pragma unroll
    for (int st = 8; st >= 1; st >>= 1)
        #pragma unroll
        for (int p = 0; p < 16; ++p) if (p < st) mx[p] = fmaxf(mx[p], mx[p + st]);
    float v = mx[0];
    // defer-max: skip rescale when no row grew by > 11 (log2 domain)
    if (!__all(v <= m_i + 11.0f)) {
        float vf = fmaxf(v, __shfl_xor(v, 32));
        float mnew = fmaxf(m_i, vf);
        float corr = exp2f(m_i - mnew);
        m_i = mnew;
        l_i *= corr;
        #pragma unroll
        for (int p = 0; p < 16; ++p) { o0[p] *= corr; o1[p] *= corr; }
    }
    // P = exp2(s - m), in place; row sum
    float ps[16];
    #pragma unroll
    for (int p = 0; p < 16; ++p) {
        s0[p] = exp2f(s0[p] - m_i);
        s1[p] = exp2f(s1[p] - m_i);
        ps[p] = s0[p] + s1[p];
    }
    #pragma unroll
    for (int st = 8; st >= 1; st >>= 1)
        #pragma unroll
        for (int p = 0; p < 16; ++p) if (p < st) ps[p] += ps[p + st];
    float psum = ps[0];
    psum += __shfl_xor(psum, 32);
    l_i += psum;
    // pack P -> bf16 B-frags (per 16-key subtile): 4 cvt_pk + 2 permlane32_swap each
    #pragma unroll
    for (int ks = 0; ks < 4; ++ks) {
        const f32x16& sm_ = (ks >> 1) ? s1 : s0;
        const int pb0 = (ks & 1) * 8;
        unsigned A0 = cvtpk(sm_[pb0 + 0], sm_[pb0 + 1]);
        unsigned B0 = cvtpk(sm_[pb0 + 4], sm_[pb0 + 5]);
        unsigned A1 = cvtpk(sm_[pb0 + 2], sm_[pb0 + 3]);
        unsigned B1 = cvtpk(sm_[pb0 + 6], sm_[pb0 + 7]);
        asm volatile("v_permlane32_swap_b32 %0, %1" : "+v"(A0), "+v"(B0));
        asm volatile("v_permlane32_swap_b32 %0, %1" : "+v"(A1), "+v"(B1));
        u32x4 wv = { A0, A1, B0, B1 };
        bf16x8 pb = __builtin_bit_cast(bf16x8, wv);
        o0 = __builtin_amdgcn_mfma_f32_32x32x16_bf16(av[0][ks], pb, o0, 0, 0, 0);
        o1 = __builtin_amdgcn_mfma_f32_32x32x16_bf16(av[1][ks], pb, o1, 0, 0, 0);
    }
}

__global__ __launch_bounds__(64, 2) void attn_fwd3(
    const short* __restrict__ qb, const short* __restrict__ kb,
    const short* __restrict__ vt, short* __restrict__ ao)
{
    const int lane = threadIdx.x & 63;
    const int r = lane & 31, h = lane >> 5;

    // decode: 2048 blocks = 8 xcd * (4 bh * 64 strips). Global big-strip-first,
    // bh cycled fast within xcd (working set 4 heads/XCD ~ 2MB L2).
    const int bid = blockIdx.x;
    const int xcd = bid & 7, jj = bid >> 3;
    const int bh = xcd * 4 + (jj & 3);
    const int strip = 63 - (jj >> 2);
    const int qw = strip * 32;

    const short* qbase = qb + (size_t)bh * (2048 * 64);
    const short* kbase = kb + (size_t)bh * (2048 * 64);
    const short* vbase = vt + (size_t)bh * (64 * 2048);

    // Q B-frags (persistent): col=lane&31 -> q=qw+r, k = kk*16 + h*8 + i
    bf16x8 aq[4];
    #pragma unroll
    for (int kk = 0; kk < 4; ++kk)
        aq[kk] = *(const bf16x8*)(qbase + (size_t)(qw + r) * 64 + kk * 16 + h * 8);

    float m_i = -1e30f, l_i = 0.0f;
    f32x16 o0 = {}, o1 = {};
    const int q = qw + r;

    const int nt = qw / 64 + 1;   // total K-tiles (last is masked)
    const int nm = nt - 1;        // unmasked tiles

    bf16x8 kA[2][4], kB[2][4], av[2][4];
    load_kf(kA, kbase, 0, r, h);

    int kt = 0;
#define TILE_UNMASKED(KCUR, KNXT)                                     \
    {                                                                  \
        load_vf(av, vbase, kt * 64, r, h);                             \
        f32x16 s0 = {}, s1 = {};                                       \
        qk_mfma(s0, s1, KCUR, aq);                                     \
        load_kf(KNXT, kbase, (kt + 1) * 64, r, h);                     \
        sm_pv<false>(s0, s1, av, kt * 64, q, h, m_i, l_i, o0, o1);     \
        ++kt;                                                          \
    }
#define TILE_MASKED(KCUR)                                              \
    {                                                                  \
        load_vf(av, vbase, kt * 64, r, h);                             \
        f32x16 s0 = {}, s1 = {};                                       \
        qk_mfma(s0, s1, KCUR, aq);                                     \
        sm_pv<true>(s0, s1, av, kt * 64, q, h, m_i, l_i, o0, o1);      \
    }

    while (kt < nm) {
        TILE_UNMASKED(kA, kB);
        if (kt >= nm) break;
        TILE_UNMASKED(kB, kA);
    }
    // masked last tile: tile t lives in kA iff t even
    if (nm & 1) { TILE_MASKED(kB); }
    else        { TILE_MASKED(kA); }
#undef TILE_UNMASKED
#undef TILE_MASKED

    // epilogue: normalize, store O[q][d] to ao (B,S,D) bf16
    const float rl = 1.0f / l_i;
    const int b = bh >> 4, hh = bh & 15;
    short* aob = ao + ((size_t)(b * 2048 + q)) * 1024 + hh * 64;
    #pragma unroll
    for (int dm = 0; dm < 2; ++dm) {
        const f32x16& o = dm ? o1 : o0;
        #pragma unroll
        for (int g = 0; g < 4; ++g) {
            int d = dm * 32 + g * 8 + h * 4;
            bf16x4 o4 = { f2bf(o[4 * g + 0] * rl), f2bf(o[4 * g + 1] * rl),
                          f2bf(o[4 * g + 2] * rl), f2bf(o[4 * g + 3] * rl) };
            *(bf16x4*)(aob + d) = o4;
        }
    }
}

extern "C" void kernel_launch(void* const* d_in, const int* in_sizes, int n_in,
                              void* d_out, int out_size, void* d_ws, size_t ws_size,
                              hipStream_t stream) {
    const float* queries = (const float*)d_in[0];
    const float* keys    = (const float*)d_in[1];
    const float* values  = (const float*)d_in[2];
    const float* Wq = (const float*)d_in[3];  const float* bq = (const float*)d_in[4];
    const float* Wk = (const float*)d_in[5];  const float* bk = (const float*)d_in[6];
    const float* Wv = (const float*)d_in[7];  const float* bv = (const float*)d_in[8];
    const float* Wo = (const float*)d_in[9];  const float* bo = (const float*)d_in[10];
    float* out = (float*)d_out;

    char* ws = (char*)d_ws;
    short* xb = (short*)(ws);                   // 24MB
    short* qb = (short*)(ws + (24u << 20));     // 8MB
    short* kb = (short*)(ws + (32u << 20));     // 8MB
    short* vt = (short*)(ws + (40u << 20));     // 8MB
    short* wb = (short*)(ws + (48u << 20));     // 8MB
    short* ao = (short*)(ws);                   // 8MB, reuses xb after qkv_gemm

    cvt_x<<<6144, 256, 0, stream>>>(queries, keys, values, xb);
    cvt_w<<<dim3(16, 16, 4), 256, 0, stream>>>(Wq, Wk, Wv, Wo, wb);
    qkv_gemm<<<dim3(8, 32, 3), 256, 0, stream>>>(xb, wb, bq, bk, bv, qb, kb, vt);
    attn_fwd3<<<2048, 64, 0, stream>>>(qb, kb, vt, ao);
    out_gemm<<<dim3(8, 32), 256, 0, stream>>>(ao, wb + (size_t)3 * 1048576, bo, out);
}